// Round 1
// baseline (318.468 us; speedup 1.0000x reference)
//
#include <hip/hip_runtime.h>

constexpr int BSZ = 4096;
constexpr int DIM = 1024;
constexpr float EPS = 0.05f;
constexpr float REGW = 0.1f;
constexpr float INVB = 1.0f / 4096.0f;

typedef __bf16 bf16x8 __attribute__((ext_vector_type(8)));
typedef float  f32x4  __attribute__((ext_vector_type(4)));

__device__ __forceinline__ unsigned short f2bf(float f) {
  unsigned u = __float_as_uint(f);
  u += 0x7fffu + ((u >> 16) & 1u);   // round-to-nearest-even
  return (unsigned short)(u >> 16);
}
__device__ __forceinline__ float bflo(unsigned w) { return __uint_as_float(w << 16); }
__device__ __forceinline__ float bfhi(unsigned w) { return __uint_as_float(w & 0xffff0000u); }

// ---------------- 1) row-normalize fp32 -> bf16 ----------------
// grid: 8192 blocks x 256 thr. blocks [0,4096): audio->AN, [4096,8192): text->TN
__global__ void k_rownorm(const float* __restrict__ audio, const float* __restrict__ text,
                          unsigned short* __restrict__ AN, unsigned short* __restrict__ TN) {
  int row = blockIdx.x;
  const float* src;
  unsigned short* dst;
  if (row < BSZ) { src = audio + (size_t)row * DIM; dst = AN + (size_t)row * DIM; }
  else           { src = text + (size_t)(row - BSZ) * DIM; dst = TN + (size_t)(row - BSZ) * DIM; }
  int t = threadIdx.x;
  float4 x = ((const float4*)src)[t];
  float ss = x.x * x.x + x.y * x.y + x.z * x.z + x.w * x.w;
#pragma unroll
  for (int off = 32; off > 0; off >>= 1) ss += __shfl_down(ss, off);
  __shared__ float red[4];
  int lane = t & 63, w = t >> 6;
  if (lane == 0) red[w] = ss;
  __syncthreads();
  float rn = rsqrtf(red[0] + red[1] + red[2] + red[3]);
  ushort4 o;
  o.x = f2bf(x.x * rn); o.y = f2bf(x.y * rn);
  o.z = f2bf(x.z * rn); o.w = f2bf(x.w * rn);
  ((ushort4*)dst)[t] = o;
}

// ---------------- 2) GEMM: G = AN @ TN^T (bf16 out) + per-block min ----------------
// 128x128 tile, BK=32, 256 thr (4 waves, 2x2), 16x16x32 bf16 MFMA, 4x4 accs/wave.
constexpr int LDT = 40;  // padded LDS row stride (elements)

__global__ __launch_bounds__(256) void k_gemm(const unsigned short* __restrict__ A,
                                              const unsigned short* __restrict__ Bt,
                                              unsigned short* __restrict__ G,
                                              float* __restrict__ minpart) {
  __shared__ __align__(16) unsigned short As[128 * LDT];
  __shared__ __align__(16) unsigned short Bs[128 * LDT];
  int t = threadIdx.x;
  int lane = t & 63, w = t >> 6;
  int wr = w >> 1, wc = w & 1;
  int i0 = blockIdx.y * 128, j0 = blockIdx.x * 128;
  f32x4 zero = {0.f, 0.f, 0.f, 0.f};
  f32x4 acc[4][4];
#pragma unroll
  for (int mi = 0; mi < 4; mi++)
#pragma unroll
    for (int ni = 0; ni < 4; ni++) acc[mi][ni] = zero;
  int sr = t >> 2, sc = t & 3;
  const size_t aoff = (size_t)(i0 + sr) * DIM + sc * 8;
  const size_t boff = (size_t)(j0 + sr) * DIM + sc * 8;
  int rb = lane & 15;
  int kb = (lane >> 4) * 8;
  for (int k0 = 0; k0 < DIM; k0 += 32) {
    __syncthreads();
    *(uint4*)&As[sr * LDT + sc * 8]        = *(const uint4*)&A[aoff + k0];
    *(uint4*)&As[(sr + 64) * LDT + sc * 8] = *(const uint4*)&A[aoff + (size_t)64 * DIM + k0];
    *(uint4*)&Bs[sr * LDT + sc * 8]        = *(const uint4*)&Bt[boff + k0];
    *(uint4*)&Bs[(sr + 64) * LDT + sc * 8] = *(const uint4*)&Bt[boff + (size_t)64 * DIM + k0];
    __syncthreads();
    bf16x8 af[4], bfr[4];
#pragma unroll
    for (int mi = 0; mi < 4; mi++)
      af[mi] = *(const bf16x8*)&As[(wr * 64 + mi * 16 + rb) * LDT + kb];
#pragma unroll
    for (int ni = 0; ni < 4; ni++)
      bfr[ni] = *(const bf16x8*)&Bs[(wc * 64 + ni * 16 + rb) * LDT + kb];
#pragma unroll
    for (int mi = 0; mi < 4; mi++)
#pragma unroll
      for (int ni = 0; ni < 4; ni++)
        acc[mi][ni] = __builtin_amdgcn_mfma_f32_16x16x32_bf16(af[mi], bfr[ni], acc[mi][ni], 0, 0, 0);
  }
  // epilogue: C/D layout col=lane&15, row=(lane>>4)*4+reg  [m89-verified]
  float mn = 3.0e38f;
  int cq = lane & 15, rq = lane >> 4;
#pragma unroll
  for (int mi = 0; mi < 4; mi++) {
#pragma unroll
    for (int ni = 0; ni < 4; ni++) {
#pragma unroll
      for (int r = 0; r < 4; r++) {
        float gv = acc[mi][ni][r];
        mn = fminf(mn, gv);
        int gi = i0 + wr * 64 + mi * 16 + rq * 4 + r;
        int gj = j0 + wc * 64 + ni * 16 + cq;
        G[(size_t)gi * BSZ + gj] = f2bf(gv);
      }
    }
  }
#pragma unroll
  for (int off = 32; off > 0; off >>= 1) mn = fminf(mn, __shfl_down(mn, off));
  __shared__ float rm[4];
  if (lane == 0) rm[w] = mn;
  __syncthreads();
  if (t == 0) minpart[blockIdx.y * 32 + blockIdx.x] = fminf(fminf(rm[0], rm[1]), fminf(rm[2], rm[3]));
}

// ---------------- 3) reduce min -> scale; init u ----------------
__global__ void k_prep(const float* __restrict__ minpart, float* __restrict__ scalars,
                       float* __restrict__ u) {
  int t = threadIdx.x;
  float mn = 3.0e38f;
  for (int i = t; i < 1024; i += 256) mn = fminf(mn, minpart[i]);
#pragma unroll
  for (int off = 32; off > 0; off >>= 1) mn = fminf(mn, __shfl_down(mn, off));
  __shared__ float rm[4];
  int lane = t & 63, w = t >> 6;
  if (lane == 0) rm[w] = mn;
  __syncthreads();
  if (t == 0) {
    float gmin = fminf(fminf(rm[0], rm[1]), fminf(rm[2], rm[3]));
    float mmax = 1.0f - gmin;          // max(M) = 1 - min(G)
    scalars[0] = 1.0f / (EPS * mmax);  // K = exp((g-1)*scale)
  }
  for (int i = t; i < BSZ; i += 256) u[i] = INVB;
}

// ---------------- 4) K = exp((G-1)*s) in place; also write K^T ----------------
constexpr int TP = 72;  // padded transpose-tile stride (elements)
__global__ void k_expk(unsigned short* __restrict__ KK, unsigned short* __restrict__ KT,
                       const float* __restrict__ scalars) {
  __shared__ __align__(16) unsigned short tile[64 * TP];
  float s = scalars[0];
  int i0 = blockIdx.y * 64, j0 = blockIdx.x * 64;
  int t = threadIdx.x;
  int r = t >> 3, c = (t & 7) * 8;
#pragma unroll
  for (int p = 0; p < 2; p++) {
    int rr = r + p * 32;
    size_t off = (size_t)(i0 + rr) * BSZ + j0 + c;
    uint4 gv = *(const uint4*)&KK[off];
    unsigned ww[4] = {gv.x, gv.y, gv.z, gv.w};
#pragma unroll
    for (int e = 0; e < 4; e++) {
      float g0 = bflo(ww[e]), g1 = bfhi(ww[e]);
      unsigned short h0 = f2bf(__expf((g0 - 1.0f) * s));
      unsigned short h1 = f2bf(__expf((g1 - 1.0f) * s));
      ww[e] = (unsigned)h0 | ((unsigned)h1 << 16);
      tile[(c + 2 * e) * TP + rr] = h0;
      tile[(c + 2 * e + 1) * TP + rr] = h1;
    }
    uint4 ov; ov.x = ww[0]; ov.y = ww[1]; ov.z = ww[2]; ov.w = ww[3];
    *(uint4*)&KK[off] = ov;
  }
  __syncthreads();
#pragma unroll
  for (int p = 0; p < 2; p++) {
    int rr = r + p * 32;
    uint4 ov = *(const uint4*)&tile[rr * TP + c];
    *(uint4*)&KT[(size_t)(j0 + rr) * BSZ + i0 + c] = ov;
  }
}

// ---------------- 5) Sinkhorn matvec: outv = INVB / (M @ x) ----------------
// grid 1024 x 256 thr; wave per row; x staged in LDS.
__global__ void k_matvec(const unsigned short* __restrict__ M, const float* __restrict__ x,
                         float* __restrict__ outv) {
  __shared__ float xs[BSZ];
  int t = threadIdx.x, lane = t & 63, w = t >> 6;
  for (int i = t; i < BSZ / 4; i += 256) ((float4*)xs)[i] = ((const float4*)x)[i];
  __syncthreads();
  int row = blockIdx.x * 4 + w;
  const unsigned short* mrow = M + (size_t)row * BSZ;
  float acc = 0.f;
#pragma unroll
  for (int it = 0; it < 8; it++) {
    int j = it * 512 + lane * 8;
    uint4 kv = *(const uint4*)&mrow[j];
    float4 x0 = *(const float4*)&xs[j];
    float4 x1 = *(const float4*)&xs[j + 4];
    acc += bflo(kv.x) * x0.x + bfhi(kv.x) * x0.y
         + bflo(kv.y) * x0.z + bfhi(kv.y) * x0.w
         + bflo(kv.z) * x1.x + bfhi(kv.z) * x1.y
         + bflo(kv.w) * x1.z + bfhi(kv.w) * x1.w;
  }
#pragma unroll
  for (int off = 32; off > 0; off >>= 1) acc += __shfl_down(acc, off);
  if (lane == 0) outv[row] = INVB / acc;
}

// ---------------- 6) row stats: ce terms (lse - diag) and kl_row ----------------
__global__ void k_rowstats(const unsigned short* __restrict__ K, const float* __restrict__ u,
                           const float* __restrict__ v, float* __restrict__ ce_part,
                           float* __restrict__ klr_part) {
  __shared__ float vs[BSZ];
  int t = threadIdx.x, lane = t & 63, w = t >> 6;
  for (int i = t; i < BSZ / 4; i += 256) ((float4*)vs)[i] = ((const float4*)v)[i];
  __syncthreads();
  int row = blockIdx.x * 4 + w;
  float ui = u[row];
  const unsigned short* krow = K + (size_t)row * BSZ;
  float se = 0.f, sz = 0.f, dg = 0.f;
  for (int it = 0; it < 8; it++) {
    int j = it * 512 + lane * 8;
    uint4 kv = *(const uint4*)&krow[j];
    unsigned ww[4] = {kv.x, kv.y, kv.z, kv.w};
#pragma unroll
    for (int e = 0; e < 4; e++) {
      float k0 = bflo(ww[e]), k1 = bfhi(ww[e]);
      float p0 = k0 * vs[j + 2 * e], p1 = k1 * vs[j + 2 * e + 1];
      sz += p0 + p1;
      float pi0 = ui * p0, pi1 = ui * p1;
      se += __expf(pi0) + __expf(pi1);   // pi tiny -> no max-subtraction needed
      if (j + 2 * e == row) dg = pi0;
      if (j + 2 * e + 1 == row) dg = pi1;
    }
  }
#pragma unroll
  for (int off = 32; off > 0; off >>= 1) {
    se += __shfl_down(se, off);
    sz += __shfl_down(sz, off);
    dg += __shfl_down(dg, off);
  }
  __shared__ float rce[4], rkl[4];
  if (lane == 0) {
    float rowsum = ui * sz;
    rce[w] = logf(se) - dg;
    rkl[w] = rowsum > 0.f ? rowsum * (logf(rowsum) - INVB) : 0.f;
  }
  __syncthreads();
  if (t == 0) {
    ce_part[blockIdx.x]  = rce[0] + rce[1] + rce[2] + rce[3];
    klr_part[blockIdx.x] = rkl[0] + rkl[1] + rkl[2] + rkl[3];
  }
}

// ---------------- 7) col stats: kl_col ----------------
__global__ void k_colstats(const unsigned short* __restrict__ KT, const float* __restrict__ u,
                           const float* __restrict__ v, float* __restrict__ klc_part) {
  __shared__ float us[BSZ];
  int t = threadIdx.x, lane = t & 63, w = t >> 6;
  for (int i = t; i < BSZ / 4; i += 256) ((float4*)us)[i] = ((const float4*)u)[i];
  __syncthreads();
  int col = blockIdx.x * 4 + w;
  const unsigned short* mrow = KT + (size_t)col * BSZ;
  float acc = 0.f;
#pragma unroll
  for (int it = 0; it < 8; it++) {
    int j = it * 512 + lane * 8;
    uint4 kv = *(const uint4*)&mrow[j];
    float4 x0 = *(const float4*)&us[j];
    float4 x1 = *(const float4*)&us[j + 4];
    acc += bflo(kv.x) * x0.x + bfhi(kv.x) * x0.y
         + bflo(kv.y) * x0.z + bfhi(kv.y) * x0.w
         + bflo(kv.z) * x1.x + bfhi(kv.z) * x1.y
         + bflo(kv.w) * x1.z + bfhi(kv.w) * x1.w;
  }
#pragma unroll
  for (int off = 32; off > 0; off >>= 1) acc += __shfl_down(acc, off);
  __shared__ float rk[4];
  if (lane == 0) {
    float colsum = v[col] * acc;
    rk[w] = colsum > 0.f ? colsum * (logf(colsum) - INVB) : 0.f;
  }
  __syncthreads();
  if (t == 0) klc_part[blockIdx.x] = rk[0] + rk[1] + rk[2] + rk[3];
}

// ---------------- 8) final combine ----------------
__global__ void k_finish(const float* __restrict__ ce_part, const float* __restrict__ klr_part,
                         const float* __restrict__ klc_part, float* __restrict__ out) {
  int t = threadIdx.x;
  float a = 0.f, b = 0.f, c = 0.f;
  for (int i = t; i < 1024; i += 256) { a += ce_part[i]; b += klr_part[i]; c += klc_part[i]; }
#pragma unroll
  for (int off = 32; off > 0; off >>= 1) {
    a += __shfl_down(a, off); b += __shfl_down(b, off); c += __shfl_down(c, off);
  }
  __shared__ float ra[4], rb[4], rc[4];
  int lane = t & 63, w = t >> 6;
  if (lane == 0) { ra[w] = a; rb[w] = b; rc[w] = c; }
  __syncthreads();
  if (t == 0) {
    float ce = (ra[0] + ra[1] + ra[2] + ra[3]) * INVB;
    float klr = (rb[0] + rb[1] + rb[2] + rb[3]) * INVB;
    float klc = (rc[0] + rc[1] + rc[2] + rc[3]) * INVB;
    out[0] = ce + REGW * (klc + klr);
  }
}

extern "C" void kernel_launch(void* const* d_in, const int* in_sizes, int n_in,
                              void* d_out, int out_size, void* d_ws, size_t ws_size,
                              hipStream_t stream) {
  const float* audio = (const float*)d_in[0];
  const float* text  = (const float*)d_in[1];
  float* out = (float*)d_out;
  char* ws = (char*)d_ws;

  unsigned short* KK = (unsigned short*)(ws);                  // 4096*4096*2 = 33554432 (G then K, in place)
  unsigned short* KT = (unsigned short*)(ws + 33554432);       // 33554432
  unsigned short* AN = (unsigned short*)(ws + 67108864);       // 8388608
  unsigned short* TN = (unsigned short*)(ws + 75497472);       // 8388608
  float* fbase      = (float*)(ws + 83886080);
  float* u          = fbase;          // 4096
  float* v          = fbase + 4096;   // 4096
  float* minpart    = fbase + 8192;   // 1024
  float* ce_part    = fbase + 9216;   // 1024
  float* klr_part   = fbase + 10240;  // 1024
  float* klc_part   = fbase + 11264;  // 1024
  float* scalars    = fbase + 12288;  // few

  k_rownorm<<<2 * BSZ, 256, 0, stream>>>(audio, text, AN, TN);
  k_gemm<<<dim3(32, 32), 256, 0, stream>>>(AN, TN, KK, minpart);
  k_prep<<<1, 256, 0, stream>>>(minpart, scalars, u);
  k_expk<<<dim3(64, 64), 256, 0, stream>>>(KK, KT, scalars);
  for (int it = 0; it < 10; it++) {
    k_matvec<<<1024, 256, 0, stream>>>(KT, u, v);  // v = b / (K^T u)
    k_matvec<<<1024, 256, 0, stream>>>(KK, v, u);  // u = a / (K v)
  }
  k_rowstats<<<1024, 256, 0, stream>>>(KK, u, v, ce_part, klr_part);
  k_colstats<<<1024, 256, 0, stream>>>(KT, u, v, klc_part);
  k_finish<<<1, 256, 0, stream>>>(ce_part, klr_part, klc_part, out);
}

// Round 2
// 242.984 us; speedup vs baseline: 1.3107x; 1.3107x over previous
//
#include <hip/hip_runtime.h>

constexpr int BSZ = 4096;
constexpr int DIM = 1024;
constexpr float EPS = 0.05f;
constexpr float REGW = 0.1f;
constexpr float INVB = 1.0f / 4096.0f;

typedef __bf16 bf16x8 __attribute__((ext_vector_type(8)));
typedef float  f32x4  __attribute__((ext_vector_type(4)));
typedef float  f32x2  __attribute__((ext_vector_type(2)));

__device__ __forceinline__ unsigned short f2bf(float f) {
  unsigned u = __float_as_uint(f);
  u += 0x7fffu + ((u >> 16) & 1u);
  return (unsigned short)(u >> 16);
}
__device__ __forceinline__ float bflo(unsigned w) { return __uint_as_float(w << 16); }
__device__ __forceinline__ float bfhi(unsigned w) { return __uint_as_float(w & 0xffff0000u); }

// ---- fp8 e4m3fn (OCP) encode, f in [0,1], RNE ----
__device__ __forceinline__ unsigned char f2fp8(float f) {
  if (!(f > 0.f)) return 0;
  int e; float m = frexpf(f, &e);   // f = m*2^e, m in [0.5,1)
  (void)m;
  int eu = e - 1;                    // f = (2m)*2^eu
  if (eu < -6) {                     // subnormal: quantum 2^-9
    float q = rintf(ldexpf(f, 9));
    if (q > 7.f) return 0x08;        // rounds up to min normal 2^-6
    return (unsigned char)(int)q;
  }
  float q = rintf(ldexpf(f, 3 - eu));  // in [8,16]
  int qi = (int)q;
  if (qi >= 16) { qi = 8; eu++; }
  if (eu > 8) { eu = 8; qi = 15; }     // clamp (won't happen for f<=1)
  return (unsigned char)(((eu + 7) << 3) | (qi & 7));
}

// ---- fp8 e4m3fn decode x4 (nonnegative values only) ----
__device__ __forceinline__ float fp8_1(unsigned b) {
  unsigned e = (b >> 3) & 15u, m = b & 7u;
  float n = __uint_as_float(((e + 120u) << 23) | (m << 20));
  float s = (float)(int)m * 0.001953125f;  // m * 2^-9
  return e ? n : s;
}
__device__ __forceinline__ f32x4 fp8x4(unsigned v) {
#if __has_builtin(__builtin_amdgcn_cvt_pk_f32_fp8)
  f32x2 a = __builtin_amdgcn_cvt_pk_f32_fp8(v, false);
  f32x2 b = __builtin_amdgcn_cvt_pk_f32_fp8(v, true);
  f32x4 r; r[0] = a[0]; r[1] = a[1]; r[2] = b[0]; r[3] = b[1];
  return r;
#else
  f32x4 r;
  r[0] = fp8_1(v & 255u); r[1] = fp8_1((v >> 8) & 255u);
  r[2] = fp8_1((v >> 16) & 255u); r[3] = fp8_1(v >> 24);
  return r;
#endif
}

// ---- async global->LDS, 16B per lane (wave-uniform LDS base) ----
__device__ __forceinline__ void gld16(const void* g, void* l) {
  __builtin_amdgcn_global_load_lds((__attribute__((address_space(1))) void*)(g),
                                   (__attribute__((address_space(3))) void*)(l), 16, 0, 0);
}

// ---------------- 1) row-normalize fp32 -> bf16 ----------------
__global__ void k_rownorm(const float* __restrict__ audio, const float* __restrict__ text,
                          unsigned short* __restrict__ AN, unsigned short* __restrict__ TN) {
  int row = blockIdx.x;
  const float* src;
  unsigned short* dst;
  if (row < BSZ) { src = audio + (size_t)row * DIM; dst = AN + (size_t)row * DIM; }
  else           { src = text + (size_t)(row - BSZ) * DIM; dst = TN + (size_t)(row - BSZ) * DIM; }
  int t = threadIdx.x;
  float4 x = ((const float4*)src)[t];
  float ss = x.x * x.x + x.y * x.y + x.z * x.z + x.w * x.w;
#pragma unroll
  for (int off = 32; off > 0; off >>= 1) ss += __shfl_down(ss, off);
  __shared__ float red[4];
  int lane = t & 63, w = t >> 6;
  if (lane == 0) red[w] = ss;
  __syncthreads();
  float rn = rsqrtf(red[0] + red[1] + red[2] + red[3]);
  ushort4 o;
  o.x = f2bf(x.x * rn); o.y = f2bf(x.y * rn);
  o.z = f2bf(x.z * rn); o.w = f2bf(x.w * rn);
  ((ushort4*)dst)[t] = o;
}

// ---------------- 2) GEMM: G = AN @ TN^T (bf16 out), m97-style staging ----------------
// 128x128 tile, BK=32, 256 thr (4 waves 2x2), unpadded LDS for global_load_lds.
__global__ __launch_bounds__(256) void k_gemm(const unsigned short* __restrict__ A,
                                              const unsigned short* __restrict__ Bt,
                                              unsigned short* __restrict__ G,
                                              float* __restrict__ minpart,
                                              float* __restrict__ maxpart) {
  __shared__ __align__(16) unsigned short As[128 * 32];
  __shared__ __align__(16) unsigned short Bs[128 * 32];
  int t = threadIdx.x, lane = t & 63, w = t >> 6;
  int wr = w >> 1, wc = w & 1;
  int i0 = blockIdx.y * 128, j0 = blockIdx.x * 128;
  f32x4 zero = {0.f, 0.f, 0.f, 0.f};
  f32x4 acc[4][4];
#pragma unroll
  for (int mi = 0; mi < 4; mi++)
#pragma unroll
    for (int ni = 0; ni < 4; ni++) acc[mi][ni] = zero;

  // staging: wave w stages rows [32w, 32w+32) of both tiles as two 16-row chunks.
  // chunk layout: lane l -> row l>>2, elem col (l&3)*8  (1024B per wave-issue)
  int srow = lane >> 2, scol = (lane & 3) * 8;
  const unsigned short* ga0 = A + (size_t)(i0 + w * 32 + srow) * DIM + scol;
  const unsigned short* ga1 = ga0 + (size_t)16 * DIM;
  const unsigned short* gb0 = Bt + (size_t)(j0 + w * 32 + srow) * DIM + scol;
  const unsigned short* gb1 = gb0 + (size_t)16 * DIM;
  unsigned short* la0 = &As[(w * 32) * 32];
  unsigned short* la1 = &As[(w * 32 + 16) * 32];
  unsigned short* lb0 = &Bs[(w * 32) * 32];
  unsigned short* lb1 = &Bs[(w * 32 + 16) * 32];

  int rb = lane & 15, kb = (lane >> 4) * 8;
  for (int k0 = 0; k0 < DIM; k0 += 32) {
    __syncthreads();
    gld16(ga0 + k0, la0);
    gld16(ga1 + k0, la1);
    gld16(gb0 + k0, lb0);
    gld16(gb1 + k0, lb1);
    __syncthreads();
    bf16x8 af[4], bfr[4];
#pragma unroll
    for (int mi = 0; mi < 4; mi++)
      af[mi] = *(const bf16x8*)&As[(wr * 64 + mi * 16 + rb) * 32 + kb];
#pragma unroll
    for (int ni = 0; ni < 4; ni++)
      bfr[ni] = *(const bf16x8*)&Bs[(wc * 64 + ni * 16 + rb) * 32 + kb];
#pragma unroll
    for (int mi = 0; mi < 4; mi++)
#pragma unroll
      for (int ni = 0; ni < 4; ni++)
        acc[mi][ni] = __builtin_amdgcn_mfma_f32_16x16x32_bf16(af[mi], bfr[ni], acc[mi][ni], 0, 0, 0);
  }
  // epilogue: C/D layout col=lane&15, row=(lane>>4)*4+reg
  float mn = 3.0e38f, mx = -3.0e38f;
  int cq = lane & 15, rq = lane >> 4;
#pragma unroll
  for (int mi = 0; mi < 4; mi++) {
#pragma unroll
    for (int ni = 0; ni < 4; ni++) {
#pragma unroll
      for (int r = 0; r < 4; r++) {
        float gv = acc[mi][ni][r];
        mn = fminf(mn, gv);
        mx = fmaxf(mx, gv);
        int gi = i0 + wr * 64 + mi * 16 + rq * 4 + r;
        int gj = j0 + wc * 64 + ni * 16 + cq;
        G[(size_t)gi * BSZ + gj] = f2bf(gv);
      }
    }
  }
#pragma unroll
  for (int off = 32; off > 0; off >>= 1) {
    mn = fminf(mn, __shfl_down(mn, off));
    mx = fmaxf(mx, __shfl_down(mx, off));
  }
  __shared__ float rm[4], rx[4];
  if (lane == 0) { rm[w] = mn; rx[w] = mx; }
  __syncthreads();
  if (t == 0) {
    int bid = blockIdx.y * 32 + blockIdx.x;
    minpart[bid] = fminf(fminf(rm[0], rm[1]), fminf(rm[2], rm[3]));
    maxpart[bid] = fmaxf(fmaxf(rx[0], rx[1]), fmaxf(rx[2], rx[3]));
  }
}

// ---------------- 3) scale/shift from min/max G; init u ----------------
__global__ void k_prep(const float* __restrict__ minpart, const float* __restrict__ maxpart,
                       float* __restrict__ scalars, float* __restrict__ u) {
  int t = threadIdx.x;
  float mn = 3.0e38f, mx = -3.0e38f;
  for (int i = t; i < 1024; i += 256) { mn = fminf(mn, minpart[i]); mx = fmaxf(mx, maxpart[i]); }
#pragma unroll
  for (int off = 32; off > 0; off >>= 1) {
    mn = fminf(mn, __shfl_down(mn, off));
    mx = fmaxf(mx, __shfl_down(mx, off));
  }
  __shared__ float rm[4], rx[4];
  int lane = t & 63, w = t >> 6;
  if (lane == 0) { rm[w] = mn; rx[w] = mx; }
  __syncthreads();
  if (t == 0) {
    float gmin = fminf(fminf(rm[0], rm[1]), fminf(rm[2], rm[3]));
    float gmax = fmaxf(fmaxf(rx[0], rx[1]), fmaxf(rx[2], rx[3]));
    float mmax = 1.0f - gmin;               // max(M) = 1 - min(G)
    scalars[0] = 1.0f / (EPS * mmax);       // scale
    scalars[1] = gmax;                      // shift: K' = exp((G-gmax)*scale), K' in (0,1]
  }
  for (int i = t; i < BSZ; i += 256) u[i] = INVB;
}

// ---------------- 4) K' = exp((G-maxG)*s) -> fp8 K, fp8 K^T, f32 diag ----------------
constexpr int TPB = 80;  // transpose-tile byte stride (8-aligned, breaks pow2)
__global__ void k_expk(const unsigned short* __restrict__ G, unsigned char* __restrict__ K,
                       unsigned char* __restrict__ KT, const float* __restrict__ scalars,
                       float* __restrict__ diagK) {
  __shared__ unsigned char tile[64 * TPB];
  float s = scalars[0], sh = scalars[1];
  int i0 = blockIdx.y * 64, j0 = blockIdx.x * 64;
  int t = threadIdx.x;
  int r = t >> 3, c = (t & 7) * 8;
#pragma unroll
  for (int p = 0; p < 2; p++) {
    int rr = r + p * 32;
    size_t off = (size_t)(i0 + rr) * BSZ + j0 + c;
    uint4 gv = *(const uint4*)&G[off];
    unsigned ww[4] = {gv.x, gv.y, gv.z, gv.w};
    unsigned char by[8];
#pragma unroll
    for (int e = 0; e < 4; e++) {
      float g0 = bflo(ww[e]), g1 = bfhi(ww[e]);
      float f0 = __expf((g0 - sh) * s);
      float f1 = __expf((g1 - sh) * s);
      by[2 * e] = f2fp8(f0);
      by[2 * e + 1] = f2fp8(f1);
      if (i0 + rr == j0 + c + 2 * e) diagK[i0 + rr] = f0;
      if (i0 + rr == j0 + c + 2 * e + 1) diagK[i0 + rr] = f1;
      tile[(c + 2 * e) * TPB + rr] = by[2 * e];
      tile[(c + 2 * e + 1) * TPB + rr] = by[2 * e + 1];
    }
    uint2 ov;
    ov.x = (unsigned)by[0] | ((unsigned)by[1] << 8) | ((unsigned)by[2] << 16) | ((unsigned)by[3] << 24);
    ov.y = (unsigned)by[4] | ((unsigned)by[5] << 8) | ((unsigned)by[6] << 16) | ((unsigned)by[7] << 24);
    *(uint2*)&K[off] = ov;
  }
  __syncthreads();
#pragma unroll
  for (int p = 0; p < 2; p++) {
    int rr = r + p * 32;
    uint2 tv = *(const uint2*)&tile[rr * TPB + c];
    *(uint2*)&KT[(size_t)(j0 + rr) * BSZ + i0 + c] = tv;
  }
}

// ---------------- 5) Sinkhorn matvec: outv = INVB / (M @ x), fp8 M ----------------
// wave per row; lane-contiguous reads (conflict-free LDS).
__global__ __launch_bounds__(256) void k_matvec(const unsigned char* __restrict__ M,
                                                const float* __restrict__ x,
                                                float* __restrict__ outv) {
  __shared__ float xs[BSZ];
  int t = threadIdx.x, lane = t & 63, w = t >> 6;
  for (int i = t; i < BSZ / 4; i += 256) ((float4*)xs)[i] = ((const float4*)x)[i];
  __syncthreads();
  int row = blockIdx.x * 4 + w;
  const unsigned char* mrow = M + (size_t)row * BSZ;
  float acc = 0.f;
#pragma unroll
  for (int it = 0; it < 16; it++) {
    int j = it * 256 + lane * 4;
    unsigned kv = *(const unsigned*)&mrow[j];
    float4 xv = *(const float4*)&xs[j];
    f32x4 f = fp8x4(kv);
    acc += f[0] * xv.x + f[1] * xv.y + f[2] * xv.z + f[3] * xv.w;
  }
#pragma unroll
  for (int off = 32; off > 0; off >>= 1) acc += __shfl_down(acc, off);
  if (lane == 0) outv[row] = INVB / acc;
}

// ---------------- 6) col stats: kl_col partials (uses K^T, u, v) ----------------
__global__ __launch_bounds__(256) void k_colstats(const unsigned char* __restrict__ KT,
                                                  const float* __restrict__ u,
                                                  const float* __restrict__ v,
                                                  float* __restrict__ klc_part) {
  __shared__ float us[BSZ];
  int t = threadIdx.x, lane = t & 63, w = t >> 6;
  for (int i = t; i < BSZ / 4; i += 256) ((float4*)us)[i] = ((const float4*)u)[i];
  __syncthreads();
  int col = blockIdx.x * 4 + w;
  const unsigned char* mrow = KT + (size_t)col * BSZ;
  float acc = 0.f;
#pragma unroll
  for (int it = 0; it < 16; it++) {
    int j = it * 256 + lane * 4;
    unsigned kv = *(const unsigned*)&mrow[j];
    float4 xv = *(const float4*)&us[j];
    f32x4 f = fp8x4(kv);
    acc += f[0] * xv.x + f[1] * xv.y + f[2] * xv.z + f[3] * xv.w;
  }
#pragma unroll
  for (int off = 32; off > 0; off >>= 1) acc += __shfl_down(acc, off);
  __shared__ float rk[4];
  if (lane == 0) {
    float colsum = v[col] * acc;
    rk[w] = colsum > 0.f ? colsum * (logf(colsum) - INVB) : 0.f;
  }
  __syncthreads();
  if (t == 0) klc_part[blockIdx.x] = rk[0] + rk[1] + rk[2] + rk[3];
}

// ---------------- 7) final combine ----------------
// ce_i = log(B + 1/B) - pi_ii   (rowsum==1/B exactly; sum exp(pi) = B + rowsum + O(1e-11))
// kl_row = (1/B)*(log(1/B) - 1/B)  (row sums == a exactly, as in the reference arithmetic)
__global__ void k_finish(const float* __restrict__ diagK, const float* __restrict__ u,
                         const float* __restrict__ v, const float* __restrict__ klc_part,
                         float* __restrict__ out) {
  int t = threadIdx.x;
  float s1 = 0.f, s2 = 0.f;
  for (int i = t; i < BSZ; i += 256) s1 += u[i] * diagK[i] * v[i];
  for (int i = t; i < 1024; i += 256) s2 += klc_part[i];
#pragma unroll
  for (int off = 32; off > 0; off >>= 1) {
    s1 += __shfl_down(s1, off);
    s2 += __shfl_down(s2, off);
  }
  __shared__ float r1[4], r2[4];
  int lane = t & 63, w = t >> 6;
  if (lane == 0) { r1[w] = s1; r2[w] = s2; }
  __syncthreads();
  if (t == 0) {
    float sd = r1[0] + r1[1] + r1[2] + r1[3];
    float sk = r2[0] + r2[1] + r2[2] + r2[3];
    float ce = logf((float)BSZ + INVB) - sd * INVB;
    float klr = INVB * (-logf((float)BSZ) - INVB);
    float klc = sk * INVB;
    out[0] = ce + REGW * (klc + klr);
  }
}

extern "C" void kernel_launch(void* const* d_in, const int* in_sizes, int n_in,
                              void* d_out, int out_size, void* d_ws, size_t ws_size,
                              hipStream_t stream) {
  const float* audio = (const float*)d_in[0];
  const float* text  = (const float*)d_in[1];
  float* out = (float*)d_out;
  char* ws = (char*)d_ws;

  unsigned short* G  = (unsigned short*)(ws);                 // 33554432 B
  unsigned char*  K  = (unsigned char*)(ws + 33554432);       // 16777216 B
  unsigned char*  KT = (unsigned char*)(ws + 50331648);       // 16777216 B
  unsigned short* AN = (unsigned short*)(ws + 67108864);      // 8388608 B
  unsigned short* TN = (unsigned short*)(ws + 75497472);      // 8388608 B
  float* fbase     = (float*)(ws + 83886080);
  float* u         = fbase;           // 4096
  float* v         = fbase + 4096;    // 4096
  float* minpart   = fbase + 8192;    // 1024
  float* maxpart   = fbase + 9216;    // 1024
  float* klc_part  = fbase + 10240;   // 1024
  float* diagK     = fbase + 11264;   // 4096
  float* scalars   = fbase + 15360;   // few

  k_rownorm<<<2 * BSZ, 256, 0, stream>>>(audio, text, AN, TN);
  k_gemm<<<dim3(32, 32), 256, 0, stream>>>(AN, TN, G, minpart, maxpart);
  k_prep<<<1, 256, 0, stream>>>(minpart, maxpart, scalars, u);
  k_expk<<<dim3(64, 64), 256, 0, stream>>>(G, K, KT, scalars, diagK);
  for (int it = 0; it < 10; it++) {
    k_matvec<<<1024, 256, 0, stream>>>(KT, u, v);  // v = b / (K^T u)
    k_matvec<<<1024, 256, 0, stream>>>(K, v, u);   // u = a / (K v)
  }
  k_colstats<<<1024, 256, 0, stream>>>(KT, u, v, klc_part);
  k_finish<<<1, 256, 0, stream>>>(diagK, u, v, klc_part, out);
}

// Round 3
// 177.740 us; speedup vs baseline: 1.7918x; 1.3671x over previous
//
#include <hip/hip_runtime.h>

constexpr int BSZ = 4096;
constexpr int DIM = 1024;
constexpr float EPS = 0.05f;
constexpr float REGW = 0.1f;
constexpr float INVB = 1.0f / 4096.0f;

typedef __bf16 bf16x8 __attribute__((ext_vector_type(8)));
typedef float  f32x4  __attribute__((ext_vector_type(4)));
typedef float  f32x2  __attribute__((ext_vector_type(2)));

__device__ __forceinline__ unsigned short f2bf(float f) {
  unsigned u = __float_as_uint(f);
  u += 0x7fffu + ((u >> 16) & 1u);
  return (unsigned short)(u >> 16);
}
__device__ __forceinline__ float bflo(unsigned w) { return __uint_as_float(w << 16); }
__device__ __forceinline__ float bfhi(unsigned w) { return __uint_as_float(w & 0xffff0000u); }

// ---- fp8 e4m3fn (OCP) encode fallback, f in [0,1], RNE ----
__device__ __forceinline__ unsigned char f2fp8(float f) {
  if (!(f > 0.f)) return 0;
  int e; frexpf(f, &e);
  int eu = e - 1;
  if (eu < -6) {
    float q = rintf(ldexpf(f, 9));
    if (q > 7.f) return 0x08;
    return (unsigned char)(int)q;
  }
  float q = rintf(ldexpf(f, 3 - eu));
  int qi = (int)q;
  if (qi >= 16) { qi = 8; eu++; }
  if (eu > 8) { eu = 8; qi = 15; }
  return (unsigned char)(((eu + 7) << 3) | (qi & 7));
}

// pack 4 floats -> 4 fp8 bytes
__device__ __forceinline__ unsigned pk_fp8x4(float f0, float f1, float f2, float f3) {
#if __has_builtin(__builtin_amdgcn_cvt_pk_fp8_f32)
  int r = __builtin_amdgcn_cvt_pk_fp8_f32(f0, f1, 0, false);
  r = __builtin_amdgcn_cvt_pk_fp8_f32(f2, f3, r, true);
  return (unsigned)r;
#else
  return (unsigned)f2fp8(f0) | ((unsigned)f2fp8(f1) << 8) |
         ((unsigned)f2fp8(f2) << 16) | ((unsigned)f2fp8(f3) << 24);
#endif
}

// ---- fp8 e4m3fn decode x4 (nonnegative values only) ----
__device__ __forceinline__ float fp8_1(unsigned b) {
  unsigned e = (b >> 3) & 15u, m = b & 7u;
  float n = __uint_as_float(((e + 120u) << 23) | (m << 20));
  float s = (float)(int)m * 0.001953125f;
  return e ? n : s;
}
__device__ __forceinline__ f32x4 fp8x4(unsigned v) {
#if __has_builtin(__builtin_amdgcn_cvt_pk_f32_fp8)
  f32x2 a = __builtin_amdgcn_cvt_pk_f32_fp8(v, false);
  f32x2 b = __builtin_amdgcn_cvt_pk_f32_fp8(v, true);
  f32x4 r; r[0] = a[0]; r[1] = a[1]; r[2] = b[0]; r[3] = b[1];
  return r;
#else
  f32x4 r;
  r[0] = fp8_1(v & 255u); r[1] = fp8_1((v >> 8) & 255u);
  r[2] = fp8_1((v >> 16) & 255u); r[3] = fp8_1(v >> 24);
  return r;
#endif
}

// ---- async global->LDS, 16B per lane ----
__device__ __forceinline__ void gld16(const void* g, void* l) {
  __builtin_amdgcn_global_load_lds((__attribute__((address_space(1))) void*)(g),
                                   (__attribute__((address_space(3))) void*)(l), 16, 0, 0);
}

// ---------------- 1) row-normalize fp32 -> bf16 ----------------
__global__ void k_rownorm(const float* __restrict__ audio, const float* __restrict__ text,
                          unsigned short* __restrict__ AN, unsigned short* __restrict__ TN) {
  int row = blockIdx.x;
  const float* src;
  unsigned short* dst;
  if (row < BSZ) { src = audio + (size_t)row * DIM; dst = AN + (size_t)row * DIM; }
  else           { src = text + (size_t)(row - BSZ) * DIM; dst = TN + (size_t)(row - BSZ) * DIM; }
  int t = threadIdx.x;
  float4 x = ((const float4*)src)[t];
  float ss = x.x * x.x + x.y * x.y + x.z * x.z + x.w * x.w;
#pragma unroll
  for (int off = 32; off > 0; off >>= 1) ss += __shfl_down(ss, off);
  __shared__ float red[4];
  int lane = t & 63, w = t >> 6;
  if (lane == 0) red[w] = ss;
  __syncthreads();
  float rn = rsqrtf(red[0] + red[1] + red[2] + red[3]);
  ushort4 o;
  o.x = f2bf(x.x * rn); o.y = f2bf(x.y * rn);
  o.z = f2bf(x.z * rn); o.w = f2bf(x.w * rn);
  ((ushort4*)dst)[t] = o;
}

// ---------------- 2) GEMM: G = AN @ TN^T (bf16 out) ----------------
__global__ __launch_bounds__(256) void k_gemm(const unsigned short* __restrict__ A,
                                              const unsigned short* __restrict__ Bt,
                                              unsigned short* __restrict__ G,
                                              float* __restrict__ minpart,
                                              float* __restrict__ maxpart) {
  __shared__ __align__(16) unsigned short As[128 * 32];
  __shared__ __align__(16) unsigned short Bs[128 * 32];
  int t = threadIdx.x, lane = t & 63, w = t >> 6;
  int wr = w >> 1, wc = w & 1;
  int i0 = blockIdx.y * 128, j0 = blockIdx.x * 128;
  f32x4 zero = {0.f, 0.f, 0.f, 0.f};
  f32x4 acc[4][4];
#pragma unroll
  for (int mi = 0; mi < 4; mi++)
#pragma unroll
    for (int ni = 0; ni < 4; ni++) acc[mi][ni] = zero;

  int srow = lane >> 2, scol = (lane & 3) * 8;
  const unsigned short* ga0 = A + (size_t)(i0 + w * 32 + srow) * DIM + scol;
  const unsigned short* ga1 = ga0 + (size_t)16 * DIM;
  const unsigned short* gb0 = Bt + (size_t)(j0 + w * 32 + srow) * DIM + scol;
  const unsigned short* gb1 = gb0 + (size_t)16 * DIM;
  unsigned short* la0 = &As[(w * 32) * 32];
  unsigned short* la1 = &As[(w * 32 + 16) * 32];
  unsigned short* lb0 = &Bs[(w * 32) * 32];
  unsigned short* lb1 = &Bs[(w * 32 + 16) * 32];

  int rb = lane & 15, kb = (lane >> 4) * 8;
  for (int k0 = 0; k0 < DIM; k0 += 32) {
    __syncthreads();
    gld16(ga0 + k0, la0);
    gld16(ga1 + k0, la1);
    gld16(gb0 + k0, lb0);
    gld16(gb1 + k0, lb1);
    __syncthreads();
    bf16x8 af[4], bfr[4];
#pragma unroll
    for (int mi = 0; mi < 4; mi++)
      af[mi] = *(const bf16x8*)&As[(wr * 64 + mi * 16 + rb) * 32 + kb];
#pragma unroll
    for (int ni = 0; ni < 4; ni++)
      bfr[ni] = *(const bf16x8*)&Bs[(wc * 64 + ni * 16 + rb) * 32 + kb];
#pragma unroll
    for (int mi = 0; mi < 4; mi++)
#pragma unroll
      for (int ni = 0; ni < 4; ni++)
        acc[mi][ni] = __builtin_amdgcn_mfma_f32_16x16x32_bf16(af[mi], bfr[ni], acc[mi][ni], 0, 0, 0);
  }
  float mn = 3.0e38f, mx = -3.0e38f;
  int cq = lane & 15, rq = lane >> 4;
#pragma unroll
  for (int mi = 0; mi < 4; mi++) {
#pragma unroll
    for (int ni = 0; ni < 4; ni++) {
#pragma unroll
      for (int r = 0; r < 4; r++) {
        float gv = acc[mi][ni][r];
        mn = fminf(mn, gv);
        mx = fmaxf(mx, gv);
        int gi = i0 + wr * 64 + mi * 16 + rq * 4 + r;
        int gj = j0 + wc * 64 + ni * 16 + cq;
        G[(size_t)gi * BSZ + gj] = f2bf(gv);
      }
    }
  }
#pragma unroll
  for (int off = 32; off > 0; off >>= 1) {
    mn = fminf(mn, __shfl_down(mn, off));
    mx = fmaxf(mx, __shfl_down(mx, off));
  }
  __shared__ float rm[4], rx[4];
  if (lane == 0) { rm[w] = mn; rx[w] = mx; }
  __syncthreads();
  if (t == 0) {
    int bid = blockIdx.y * 32 + blockIdx.x;
    minpart[bid] = fminf(fminf(rm[0], rm[1]), fminf(rm[2], rm[3]));
    maxpart[bid] = fmaxf(fmaxf(rx[0], rx[1]), fmaxf(rx[2], rx[3]));
  }
}

// ---------------- 3) scale/shift from min/max G ----------------
__global__ void k_prep(const float* __restrict__ minpart, const float* __restrict__ maxpart,
                       float* __restrict__ scalars) {
  int t = threadIdx.x;
  float mn = 3.0e38f, mx = -3.0e38f;
  for (int i = t; i < 1024; i += 256) { mn = fminf(mn, minpart[i]); mx = fmaxf(mx, maxpart[i]); }
#pragma unroll
  for (int off = 32; off > 0; off >>= 1) {
    mn = fminf(mn, __shfl_down(mn, off));
    mx = fmaxf(mx, __shfl_down(mx, off));
  }
  __shared__ float rm[4], rx[4];
  int lane = t & 63, w = t >> 6;
  if (lane == 0) { rm[w] = mn; rx[w] = mx; }
  __syncthreads();
  if (t == 0) {
    float gmin = fminf(fminf(rm[0], rm[1]), fminf(rm[2], rm[3]));
    float gmax = fmaxf(fmaxf(rx[0], rx[1]), fmaxf(rx[2], rx[3]));
    scalars[0] = 1.0f / (EPS * (1.0f - gmin));  // scale
    scalars[1] = gmax;                          // shift: K' = exp((G-gmax)*scale) in (0,1]
  }
}

// ---------------- 4) elementwise: K' = exp((G-maxG)*s) -> fp8; f32 diag ----------------
// grid 8192 x 256 thr, 8 elems/thread
__global__ __launch_bounds__(256) void k_expk(const unsigned short* __restrict__ G,
                                              unsigned char* __restrict__ K,
                                              const float* __restrict__ scalars,
                                              float* __restrict__ diagK) {
  float s = scalars[0], sh = scalars[1];
  size_t base = ((size_t)blockIdx.x * 256 + threadIdx.x) * 8;
  uint4 gv = *(const uint4*)&G[base];
  unsigned ww[4] = {gv.x, gv.y, gv.z, gv.w};
  int i = (int)(base >> 12);
  int d = i - (int)(base & 4095);  // diag element offset within [0,8) if present
  float f[8];
#pragma unroll
  for (int e = 0; e < 4; e++) {
    f[2 * e]     = __expf((bflo(ww[e]) - sh) * s);
    f[2 * e + 1] = __expf((bfhi(ww[e]) - sh) * s);
  }
  if ((unsigned)d < 8u) diagK[i] = f[d];
  uint2 ov;
  ov.x = pk_fp8x4(f[0], f[1], f[2], f[3]);
  ov.y = pk_fp8x4(f[4], f[5], f[6], f[7]);
  *(uint2*)&K[base] = ov;
}

// ---------------- 5) strip-partial column sums: colpart[strip][j] = sum_{i in strip} w_i*K_ij ----
// grid (4 colgroups, 64 strips of 64 rows), 256 thr, 4 cols/thread. w==null -> weight 1.
__global__ __launch_bounds__(256) void k_colsum(const unsigned char* __restrict__ K,
                                                const float* __restrict__ w,
                                                float* __restrict__ colpart) {
  int t = threadIdx.x;
  int c0 = blockIdx.x * 1024 + t * 4;
  int r0 = blockIdx.y * 64;
  f32x4 acc = {0.f, 0.f, 0.f, 0.f};
  for (int r = 0; r < 64; r++) {
    unsigned kv = *(const unsigned*)&K[(size_t)(r0 + r) * BSZ + c0];
    f32x4 fv = fp8x4(kv);
    float wt = w ? w[r0 + r] : 1.0f;
    acc += fv * wt;
  }
  *(f32x4*)&colpart[(size_t)blockIdx.y * BSZ + c0] = acc;
}

// ---------------- 6) v = 1 / colsum  (v = b/(K^T u0) with u0 uniform) ----------------
// grid 4 x 256 thr
__global__ void k_vcalc(const float* __restrict__ colpart, float* __restrict__ v) {
  int t = threadIdx.x;
  int c0 = blockIdx.x * 1024;
  float s[4] = {0.f, 0.f, 0.f, 0.f};
  for (int strip = 0; strip < 64; strip++) {
#pragma unroll
    for (int e = 0; e < 4; e++)
      s[e] += colpart[(size_t)strip * BSZ + c0 + e * 256 + t];
  }
#pragma unroll
  for (int e = 0; e < 4; e++) v[c0 + e * 256 + t] = 1.0f / s[e];
}

// ---------------- 7) row matvec: u = INVB / (K @ v) ----------------
__global__ __launch_bounds__(256) void k_matvec(const unsigned char* __restrict__ M,
                                                const float* __restrict__ x,
                                                float* __restrict__ outv) {
  __shared__ float xs[BSZ];
  int t = threadIdx.x, lane = t & 63, w = t >> 6;
  for (int i = t; i < BSZ / 4; i += 256) ((float4*)xs)[i] = ((const float4*)x)[i];
  __syncthreads();
  int row = blockIdx.x * 4 + w;
  const unsigned char* mrow = M + (size_t)row * BSZ;
  float acc = 0.f;
#pragma unroll
  for (int it = 0; it < 16; it++) {
    int j = it * 256 + lane * 4;
    unsigned kv = *(const unsigned*)&mrow[j];
    float4 xv = *(const float4*)&xs[j];
    f32x4 f = fp8x4(kv);
    acc += f[0] * xv.x + f[1] * xv.y + f[2] * xv.z + f[3] * xv.w;
  }
#pragma unroll
  for (int off = 32; off > 0; off >>= 1) acc += __shfl_down(acc, off);
  if (lane == 0) outv[row] = INVB / acc;
}

// ---------------- 8) klc partials from T-strip-partials ----------------
// col_j = v_j * T_j ; term = col*(log col - INVB). grid 4 x 256.
__global__ void k_klc(const float* __restrict__ colpart, const float* __restrict__ v,
                      float* __restrict__ klc_part) {
  int t = threadIdx.x;
  int c0 = blockIdx.x * 1024;
  float s[4] = {0.f, 0.f, 0.f, 0.f};
  for (int strip = 0; strip < 64; strip++) {
#pragma unroll
    for (int e = 0; e < 4; e++)
      s[e] += colpart[(size_t)strip * BSZ + c0 + e * 256 + t];
  }
  float term = 0.f;
#pragma unroll
  for (int e = 0; e < 4; e++) {
    float col = v[c0 + e * 256 + t] * s[e];
    term += col > 0.f ? col * (logf(col) - INVB) : 0.f;
  }
#pragma unroll
  for (int off = 32; off > 0; off >>= 1) term += __shfl_down(term, off);
  __shared__ float rk[4];
  int lane = t & 63, w = t >> 6;
  if (lane == 0) rk[w] = term;
  __syncthreads();
  if (t == 0) klc_part[blockIdx.x] = rk[0] + rk[1] + rk[2] + rk[3];
}

// ---------------- 9) final combine ----------------
__global__ void k_finish(const float* __restrict__ diagK, const float* __restrict__ u,
                         const float* __restrict__ v, const float* __restrict__ klc_part,
                         float* __restrict__ out) {
  int t = threadIdx.x;
  float s1 = 0.f;
  for (int i = t; i < BSZ; i += 256) s1 += u[i] * diagK[i] * v[i];
#pragma unroll
  for (int off = 32; off > 0; off >>= 1) s1 += __shfl_down(s1, off);
  __shared__ float r1[4];
  int lane = t & 63, w = t >> 6;
  if (lane == 0) r1[w] = s1;
  __syncthreads();
  if (t == 0) {
    float sd = r1[0] + r1[1] + r1[2] + r1[3];
    float sk = klc_part[0] + klc_part[1] + klc_part[2] + klc_part[3];
    float ce = logf((float)BSZ + INVB) - sd * INVB;
    float klr = INVB * (-logf((float)BSZ) - INVB);
    float klc = sk * INVB;
    out[0] = ce + REGW * (klc + klr);
  }
}

extern "C" void kernel_launch(void* const* d_in, const int* in_sizes, int n_in,
                              void* d_out, int out_size, void* d_ws, size_t ws_size,
                              hipStream_t stream) {
  const float* audio = (const float*)d_in[0];
  const float* text  = (const float*)d_in[1];
  float* out = (float*)d_out;
  char* ws = (char*)d_ws;

  unsigned short* G  = (unsigned short*)(ws);                 // 33554432 B
  unsigned char*  K  = (unsigned char*)(ws + 33554432);       // 16777216 B
  unsigned short* AN = (unsigned short*)(ws + 50331648);      // 8388608 B
  unsigned short* TN = (unsigned short*)(ws + 58720256);      // 8388608 B
  float* colpart     = (float*)(ws + 67108864);               // 64*4096*4 = 1048576 B
  float* fbase       = (float*)(ws + 68157440);
  float* u         = fbase;           // 4096
  float* v         = fbase + 4096;    // 4096
  float* minpart   = fbase + 8192;    // 1024
  float* maxpart   = fbase + 9216;    // 1024
  float* klc_part  = fbase + 10240;   // 16
  float* diagK     = fbase + 10256;   // 4096
  float* scalars   = fbase + 14352;   // few

  k_rownorm<<<2 * BSZ, 256, 0, stream>>>(audio, text, AN, TN);
  k_gemm<<<dim3(32, 32), 256, 0, stream>>>(AN, TN, G, minpart, maxpart);
  k_prep<<<1, 256, 0, stream>>>(minpart, maxpart, scalars);
  k_expk<<<8192, 256, 0, stream>>>(G, K, scalars, diagK);
  k_colsum<<<dim3(4, 64), 256, 0, stream>>>(K, nullptr, colpart);   // S_j
  k_vcalc<<<4, 256, 0, stream>>>(colpart, v);                       // v = 1/S
  k_matvec<<<1024, 256, 0, stream>>>(K, v, u);                      // u = a/(Kv)
  k_colsum<<<dim3(4, 64), 256, 0, stream>>>(K, u, colpart);         // T_j
  k_klc<<<4, 256, 0, stream>>>(colpart, v, klc_part);
  k_finish<<<1, 256, 0, stream>>>(diagK, u, v, klc_part, out);
}